// Round 24
// baseline (36.585 us; speedup 1.0000x reference)
//
#include <hip/hip_runtime.h>

typedef unsigned int uint;
typedef unsigned short ushort_t;
typedef __attribute__((ext_vector_type(8))) short short8v;   // 8 bf16 (4 VGPRs)
typedef __attribute__((ext_vector_type(4))) float f32x4;

#define BATCH 8
#define HH 128
#define WW 128
#define CC 64
#define NPIX (BATCH * HH * WW)   // 131072
#define KK 9
#define BN_EPS 1e-3f
#define ROWS 4                    // output rows per block
#define NBLK (NPIX / (64 * ROWS)) // 512 blocks

__device__ __forceinline__ uint f2bfbits(float f) {
    uint u = __float_as_uint(f);
    return (u + 0x7fffu + ((u >> 16) & 1u)) >> 16;   // RNE
}
__device__ __forceinline__ uint cvtpk(float lo, float hi) {   // packed RNE f32->2xbf16
    uint r;
    asm("v_cvt_pk_bf16_f32 %0, %1, %2" : "=v"(r) : "v"(lo), "v"(hi));
    return r;
}

// ---- setup: w1 -> bf16 [d][c]; w2 -> bf16 transposed [k][d]; fold BN ----
__global__ void setup_kernel(const float* __restrict__ w1,
                             const float* __restrict__ b1,
                             const float* __restrict__ gamma,
                             const float* __restrict__ beta,
                             const float* __restrict__ bn_mean,
                             const float* __restrict__ bn_var,
                             const float* __restrict__ w2,
                             const float* __restrict__ b2,
                             ushort_t* __restrict__ w1b,    // [64][64] bf16: w1b[d][c] = w1[c][d]
                             ushort_t* __restrict__ w2bT,   // [16][64] bf16: w2bT[k][d] = w2[d][k]
                             float* __restrict__ scalef,    // [64]
                             float* __restrict__ biasf,     // [64]
                             float* __restrict__ b2f)       // [9]
{
    int t = blockIdx.x * blockDim.x + threadIdx.x;
    int nt = gridDim.x * blockDim.x;
    for (int idx = t; idx < CC * CC; idx += nt) {
        int d = idx >> 6, c = idx & 63;
        w1b[idx] = (ushort_t)f2bfbits(w1[c * CC + d]);
    }
    for (int idx = t; idx < 16 * CC; idx += nt) {
        int k = idx >> 6, d = idx & 63;
        w2bT[idx] = (k < KK) ? (ushort_t)f2bfbits(w2[d * KK + k]) : (ushort_t)0;
    }
    if (t < CC) {
        float s = gamma[t] * rsqrtf(bn_var[t] + BN_EPS);
        scalef[t] = s;
        biasf[t] = (b1[t] - bn_mean[t]) * s + beta[t];
    }
    if (t < KK) b2f[t] = b2[t];
}

// ---- fused rolling-row kernel: ring-3 f32 rows (zero-cvt stage), 4 output rows ----
__global__ __launch_bounds__(256) void invol_fused(
    const float* __restrict__ x,
    const ushort_t* __restrict__ w1b,
    const ushort_t* __restrict__ w2bT,
    const float* __restrict__ scalef,
    const float* __restrict__ biasf,
    const float* __restrict__ b2f,
    float* __restrict__ out,     // [NPIX][64]
    float* __restrict__ kout)    // [NPIX][9]
{
    __shared__ float    xrow[3][66][68];   // ring of 3 staged rows (f32), 53856 B
    __shared__ ushort_t w1L[64][72];       // w1 tile, 9216 B
    __shared__ ushort_t w2L[16][72];       // w2^T tile, 2304 B
    __shared__ ushort_t hL[4][16][72];     // per-wave h, 9216 B (wave-private)
    __shared__ float    kS[64][12];        // kern per pixel, 3072 B (wave-private rows)
    // total 77664 B -> 2 blocks/CU (same residency as r20)

    const int t = threadIdx.x;
    const int w = __builtin_amdgcn_readfirstlane(t >> 6);
    const int l = t & 63;
    const int lq = l >> 4, lr = l & 15;
    int bid = blockIdx.x;
    bid = (bid & 7) * (NBLK / 8) + (bid >> 3);   // XCD swizzle (512 = 8*64, bijective)

    const int jhalf = bid & 1;
    const int grp = (bid >> 1) & 31;
    const int b = bid >> 6;
    const int i0 = grp * ROWS;
    const int j0 = jhalf * 64;

    auto stage_row_to_regs = [&](int ro, float4* sv) {
        const float* rowp = x + ((size_t)b * HH + min(max(ro, 0), HH - 1)) * WW * CC;
#pragma unroll
        for (int s = 0; s < 4; ++s) {
            int u = t + s * 256;
            int slot = u >> 4, c4 = u & 15;
            int jj = min(max(j0 + slot - 1, 0), WW - 1);
            sv[s] = *(const float4*)(rowp + (size_t)jj * CC + c4 * 4);
        }
        if (t < 32) {
            int u = t + 1024;
            int slot = u >> 4, c4 = u & 15;
            int jj = min(max(j0 + slot - 1, 0), WW - 1);
            sv[4] = *(const float4*)(rowp + (size_t)jj * CC + c4 * 4);
        }
    };
    auto write_row_to_lds = [&](int ringslot, const float4* sv) {   // pure copy, zero VALU
#pragma unroll
        for (int s = 0; s < 4; ++s) {
            int u = t + s * 256;
            int slot = u >> 4, c4 = u & 15;
            *(float4*)(&xrow[ringslot][slot][c4 * 4]) = sv[s];
        }
        if (t < 32) {
            int u = t + 1024;
            int slot = u >> 4, c4 = u & 15;
            *(float4*)(&xrow[ringslot][slot][c4 * 4]) = sv[4];
        }
    };

    // ---- init: stage rows i0-1, i0, i0+1 -> slots 0,1,2; weights -> LDS ----
    {
        float4 sv[5];
#pragma unroll
        for (int r = 0; r < 3; ++r) {
            stage_row_to_regs(i0 - 1 + r, sv);
            write_row_to_lds(r, sv);
        }
    }
#pragma unroll
    for (int s = 0; s < 2; ++s) {
        int u = t + s * 256;
        int row = u >> 3, seg = u & 7;
        uint4 v = *(const uint4*)(w1b + row * CC + seg * 8);
        *(uint4*)(&w1L[row][seg * 8]) = v;
    }
    if (t < 128) {
        int row = t >> 3, seg = t & 7;
        uint4 v = *(const uint4*)(w2bT + row * CC + seg * 8);
        *(uint4*)(&w2L[row][seg * 8]) = v;
    }
    __syncthreads();

    // ---- row loop (unrolled; ring slots compile-time: top=r%3, mid=(r+1)%3, bot=(r+2)%3) ----
#pragma unroll
    for (int r = 0; r < ROWS; ++r) {
        const int i = i0 + r;
        const int p0 = ((b * HH + i) * WW) + j0;
        const int sTop = r % 3, sMid = (r + 1) % 3, sBot = (r + 2) % 3;

        // T14: issue next row's global loads now (consumed after barrier at epoch end)
        float4 sv[5];
        if (r < ROWS - 1) stage_row_to_regs(i0 + r + 2, sv);

        // ---- GEMM1: wave w owns px [w*16,w*16+16); A from f32 mid slot, cvt->bf16 ----
        {
            short8v af[2];
#pragma unroll
            for (int ks = 0; ks < 2; ++ks) {
                const float* ap = &xrow[sMid][w * 16 + lr + 1][ks * 32 + lq * 8];
                float4 a0 = *(const float4*)(ap);
                float4 a1 = *(const float4*)(ap + 4);
                union { uint4 u; short8v s; } cv;
                cv.u.x = cvtpk(a0.x, a0.y);
                cv.u.y = cvtpk(a0.z, a0.w);
                cv.u.z = cvtpk(a1.x, a1.y);
                cv.u.w = cvtpk(a1.z, a1.w);
                af[ks] = cv.s;
            }

            f32x4 acc[4];
#pragma unroll
            for (int n = 0; n < 4; ++n) acc[n] = (f32x4){0.f, 0.f, 0.f, 0.f};
#pragma unroll
            for (int ks = 0; ks < 2; ++ks)
#pragma unroll
                for (int n = 0; n < 4; ++n) {
                    short8v bf = *(const short8v*)(&w1L[n * 16 + lr][ks * 32 + lq * 8]);
                    acc[n] = __builtin_amdgcn_mfma_f32_16x16x32_bf16(af[ks], bf, acc[n], 0, 0, 0);
                }
#pragma unroll
            for (int n = 0; n < 4; ++n) {
                const int d = n * 16 + lr;
                const float s = scalef[d], bb = biasf[d];
#pragma unroll
                for (int q = 0; q < 4; ++q) {
                    float hv = fmaxf(fmaf(acc[n][q], s, bb), 0.f);
                    hL[w][lq * 4 + q][d] = (ushort_t)f2bfbits(hv);
                }
            }
        }
        // same-wave LDS handoff (compiler lgkmcnt)

        // ---- GEMM2: kern = h @ w2 + b2 (M=16, N=16 pad, K=64; r9 recipe) ----
        {
            f32x4 acc2 = (f32x4){0.f, 0.f, 0.f, 0.f};
#pragma unroll
            for (int ks = 0; ks < 2; ++ks) {
                short8v a2  = *(const short8v*)(&hL[w][lr][ks * 32 + lq * 8]);
                short8v b2v = *(const short8v*)(&w2L[lr][ks * 32 + lq * 8]);
                acc2 = __builtin_amdgcn_mfma_f32_16x16x32_bf16(a2, b2v, acc2, 0, 0, 0);
            }
            if (lr < KK) {
                const float bk = b2f[lr];
#pragma unroll
                for (int q = 0; q < 4; ++q)
                    kS[w * 16 + lq * 4 + q][lr] = acc2[q] + bk;
            }
        }
        // same-wave handoff; dense kout drain: 36 contiguous float4 per wave
        {
            float* kbase = kout + (size_t)(p0 + w * 16) * KK;
            if (l < 36) {
                float v[4];
#pragma unroll
                for (int e = 0; e < 4; ++e) {
                    int f = l * 4 + e;
                    v[e] = kS[w * 16 + f / KK][f % KK];
                }
                *(f32x4*)(kbase + l * 4) = (f32x4){v[0], v[1], v[2], v[3]};
            }
        }

        // ---- involution, wave-local dense; f32 taps (no unpack, direct FMA) ----
        {
            float* obase = out + (size_t)(p0 + w * 16) * CC;
#pragma unroll
            for (int rr = 0; rr < 4; ++rr) {
                const int flat = rr * 64 + l;
                const int pxo = flat >> 4;
                const int g = flat & 15;
                const int pix = w * 16 + pxo;
                float a0 = 0.f, a1 = 0.f, a2 = 0.f, a3 = 0.f;
#pragma unroll
                for (int ti = 0; ti < 3; ++ti) {
                    const int ii = i + ti - 1;
                    if (ii < 0 || ii >= HH) continue;      // block-uniform skip
                    const int sl = (ti == 0) ? sTop : (ti == 1) ? sMid : sBot;
#pragma unroll
                    for (int tj = 0; tj < 3; ++tj) {
                        int jj = j0 + pix + tj - 1;
                        bool valid = (jj >= 0) && (jj < WW);
                        float kv = valid ? kS[pix][ti * 3 + tj] : 0.f;
                        float4 v = *(const float4*)(&xrow[sl][pix + tj][g * 4]);
                        a0 = fmaf(kv, v.x, a0);
                        a1 = fmaf(kv, v.y, a1);
                        a2 = fmaf(kv, v.z, a2);
                        a3 = fmaf(kv, v.w, a3);
                    }
                }
                *(f32x4*)(obase + (size_t)flat * 4) = (f32x4){a0, a1, a2, a3};
            }
        }

        // ---- ring-3 rotation: wait all readers done, land new row into sTop slot ----
        if (r < ROWS - 1) {
            __syncthreads();                 // all waves finished reading sTop
            write_row_to_lds(sTop, sv);      // row i+2 -> slot (r+3)%3 == sTop
            __syncthreads();                 // new row visible to all waves
        }
    }
}

extern "C" void kernel_launch(void* const* d_in, const int* in_sizes, int n_in,
                              void* d_out, int out_size, void* d_ws, size_t ws_size,
                              hipStream_t stream) {
    const float* x       = (const float*)d_in[0];
    const float* w1      = (const float*)d_in[1];
    const float* b1      = (const float*)d_in[2];
    const float* gamma   = (const float*)d_in[3];
    const float* beta    = (const float*)d_in[4];
    const float* bn_mean = (const float*)d_in[5];
    const float* bn_var  = (const float*)d_in[6];
    const float* w2      = (const float*)d_in[7];
    const float* b2      = (const float*)d_in[8];

    ushort_t* w1b  = (ushort_t*)d_ws;                // 4096 ush = 8192 B
    ushort_t* w2bT = w1b + CC * CC;                  // 1024 ush = 2048 B
    float* scalef  = (float*)(w2bT + 16 * CC);       // 64
    float* biasf   = scalef + CC;                    // 64
    float* b2f     = biasf + CC;                     // 9

    float* out  = (float*)d_out;
    float* kout = out + (size_t)NPIX * CC;

    hipLaunchKernelGGL(setup_kernel, dim3(20), dim3(256), 0, stream,
                       w1, b1, gamma, beta, bn_mean, bn_var, w2, b2,
                       w1b, w2bT, scalef, biasf, b2f);

    hipLaunchKernelGGL(invol_fused, dim3(NBLK), dim3(256), 0, stream,
                       x, w1b, w2bT, scalef, biasf, b2f, out, kout);
}

// Round 25
// 28.503 us; speedup vs baseline: 1.2836x; 1.2836x over previous
//
#include <hip/hip_runtime.h>

typedef unsigned int uint;
typedef unsigned short ushort_t;
typedef __attribute__((ext_vector_type(8))) short short8v;   // 8 bf16 (4 VGPRs)
typedef __attribute__((ext_vector_type(4))) float f32x4;

#define BATCH 8
#define HH 128
#define WW 128
#define CC 64
#define NPIX (BATCH * HH * WW)   // 131072
#define KK 9
#define BN_EPS 1e-3f
#define ROWS 4                    // output rows per block
#define NBLK (NPIX / (64 * ROWS)) // 512 = 2 blocks/CU, co-resident

__device__ __forceinline__ uint f2bfbits(float f) {
    uint u = __float_as_uint(f);
    return (u + 0x7fffu + ((u >> 16) & 1u)) >> 16;   // RNE
}
__device__ __forceinline__ float bflo(uint u) { return __uint_as_float(u << 16); }
__device__ __forceinline__ float bfhi(uint u) { return __uint_as_float(u & 0xffff0000u); }

// ---- setup: w1 -> bf16 [d][c]; w2 -> bf16 transposed [k][d]; fold BN ----
__global__ void setup_kernel(const float* __restrict__ w1,
                             const float* __restrict__ b1,
                             const float* __restrict__ gamma,
                             const float* __restrict__ beta,
                             const float* __restrict__ bn_mean,
                             const float* __restrict__ bn_var,
                             const float* __restrict__ w2,
                             const float* __restrict__ b2,
                             ushort_t* __restrict__ w1b,    // [64][64] bf16: w1b[d][c] = w1[c][d]
                             ushort_t* __restrict__ w2bT,   // [16][64] bf16: w2bT[k][d] = w2[d][k]
                             float* __restrict__ scalef,    // [64]
                             float* __restrict__ biasf,     // [64]
                             float* __restrict__ b2f)       // [9]
{
    int t = blockIdx.x * blockDim.x + threadIdx.x;
    int nt = gridDim.x * blockDim.x;
    for (int idx = t; idx < CC * CC; idx += nt) {
        int d = idx >> 6, c = idx & 63;
        w1b[idx] = (ushort_t)f2bfbits(w1[c * CC + d]);
    }
    for (int idx = t; idx < 16 * CC; idx += nt) {
        int k = idx >> 6, d = idx & 63;
        w2bT[idx] = (k < KK) ? (ushort_t)f2bfbits(w2[d * KK + k]) : (ushort_t)0;
    }
    if (t < CC) {
        float s = gamma[t] * rsqrtf(bn_var[t] + BN_EPS);
        scalef[t] = s;
        biasf[t] = (b1[t] - bn_mean[t]) * s + beta[t];
    }
    if (t < KK) b2f[t] = b2[t];
}

// ---- fused rolling-row kernel, GEMM pipelined one row ahead of involution ----
__global__ __launch_bounds__(256) void invol_fused(
    const float* __restrict__ x,
    const ushort_t* __restrict__ w1b,
    const ushort_t* __restrict__ w2bT,
    const float* __restrict__ scalef,
    const float* __restrict__ biasf,
    const float* __restrict__ b2f,
    float* __restrict__ out,     // [NPIX][64]
    float* __restrict__ kout)    // [NPIX][9]
{
    __shared__ ushort_t xrow[4][66][72];   // ring of 4 staged rows (bf16), 38016 B
    __shared__ ushort_t w1L[64][72];       // w1 tile, 9216 B
    __shared__ ushort_t w2L[16][72];       // w2^T tile, 2304 B
    __shared__ ushort_t hL[4][16][72];     // per-wave h, 9216 B (wave-private, per-epoch)
    __shared__ float    kS[2][64][12];     // kern double-buffer, 6144 B (wave-private rows)

    const int t = threadIdx.x;
    const int w = __builtin_amdgcn_readfirstlane(t >> 6);
    const int l = t & 63;
    const int lq = l >> 4, lr = l & 15;
    int bid = blockIdx.x;
    bid = (bid & 7) * (NBLK / 8) + (bid >> 3);   // XCD swizzle (512 = 8*64, bijective)

    const int jhalf = bid & 1;
    const int grp = (bid >> 1) & 31;
    const int b = bid >> 6;
    const int i0 = grp * ROWS;
    const int j0 = jhalf * 64;

    // slot(row) = (row - i0 + 1) & 3
    auto stage_row_to_regs = [&](int ro, float4* sv) {
        const float* rowp = x + ((size_t)b * HH + min(max(ro, 0), HH - 1)) * WW * CC;
#pragma unroll
        for (int s = 0; s < 4; ++s) {
            int u = t + s * 256;
            int slot = u >> 4, c4 = u & 15;
            int jj = min(max(j0 + slot - 1, 0), WW - 1);
            sv[s] = *(const float4*)(rowp + (size_t)jj * CC + c4 * 4);
        }
        if (t < 32) {
            int u = t + 1024;
            int slot = u >> 4, c4 = u & 15;
            int jj = min(max(j0 + slot - 1, 0), WW - 1);
            sv[4] = *(const float4*)(rowp + (size_t)jj * CC + c4 * 4);
        }
    };
    auto write_row_to_lds = [&](int ringslot, const float4* sv) {
#pragma unroll
        for (int s = 0; s < 4; ++s) {
            int u = t + s * 256;
            int slot = u >> 4, c4 = u & 15;
            uint2 pk;
            pk.x = f2bfbits(sv[s].x) | (f2bfbits(sv[s].y) << 16);
            pk.y = f2bfbits(sv[s].z) | (f2bfbits(sv[s].w) << 16);
            *(uint2*)(&xrow[ringslot][slot][c4 * 4]) = pk;
        }
        if (t < 32) {
            int u = t + 1024;
            int slot = u >> 4, c4 = u & 15;
            uint2 pk;
            pk.x = f2bfbits(sv[4].x) | (f2bfbits(sv[4].y) << 16);
            pk.y = f2bfbits(sv[4].z) | (f2bfbits(sv[4].w) << 16);
            *(uint2*)(&xrow[ringslot][slot][c4 * 4]) = pk;
        }
    };

    // GEMM chain for one row: A from xrow[sMid], h->hL, kern->kS[kbuf] + kout drain
    auto gemm_chain = [&](int sMid, int kbuf, int p0row) {
        // GEMM1 (r6 recipe)
        short8v af[2];
#pragma unroll
        for (int ks = 0; ks < 2; ++ks)
            af[ks] = *(const short8v*)(&xrow[sMid][w * 16 + lr + 1][ks * 32 + lq * 8]);
        f32x4 acc[4];
#pragma unroll
        for (int n = 0; n < 4; ++n) acc[n] = (f32x4){0.f, 0.f, 0.f, 0.f};
#pragma unroll
        for (int ks = 0; ks < 2; ++ks)
#pragma unroll
            for (int n = 0; n < 4; ++n) {
                short8v bf = *(const short8v*)(&w1L[n * 16 + lr][ks * 32 + lq * 8]);
                acc[n] = __builtin_amdgcn_mfma_f32_16x16x32_bf16(af[ks], bf, acc[n], 0, 0, 0);
            }
#pragma unroll
        for (int n = 0; n < 4; ++n) {
            const int d = n * 16 + lr;
            const float s = scalef[d], bb = biasf[d];
#pragma unroll
            for (int q = 0; q < 4; ++q) {
                float hv = fmaxf(fmaf(acc[n][q], s, bb), 0.f);
                hL[w][lq * 4 + q][d] = (ushort_t)f2bfbits(hv);
            }
        }
        // same-wave handoff (lgkmcnt); GEMM2 (r9 recipe)
        f32x4 acc2 = (f32x4){0.f, 0.f, 0.f, 0.f};
#pragma unroll
        for (int ks = 0; ks < 2; ++ks) {
            short8v a2  = *(const short8v*)(&hL[w][lr][ks * 32 + lq * 8]);
            short8v b2v = *(const short8v*)(&w2L[lr][ks * 32 + lq * 8]);
            acc2 = __builtin_amdgcn_mfma_f32_16x16x32_bf16(a2, b2v, acc2, 0, 0, 0);
        }
        if (lr < KK) {
            const float bk = b2f[lr];
#pragma unroll
            for (int q = 0; q < 4; ++q)
                kS[kbuf][w * 16 + lq * 4 + q][lr] = acc2[q] + bk;
        }
        // same-wave handoff; dense kout drain (36 contiguous float4 per wave)
        float* kbase = kout + (size_t)(p0row + w * 16) * KK;
        if (l < 36) {
            float v[4];
#pragma unroll
            for (int e = 0; e < 4; ++e) {
                int f = l * 4 + e;
                v[e] = kS[kbuf][w * 16 + f / KK][f % KK];
            }
            *(f32x4*)(kbase + l * 4) = (f32x4){v[0], v[1], v[2], v[3]};
        }
    };

    // ---- init: stage rows i0-1..i0+1 -> slots 0,1,2; weights -> LDS; barrier ----
    {
        float4 sv[5];
#pragma unroll
        for (int r = 0; r < 3; ++r) {
            stage_row_to_regs(i0 - 1 + r, sv);
            write_row_to_lds(r, sv);
        }
    }
#pragma unroll
    for (int s = 0; s < 2; ++s) {
        int u = t + s * 256;
        int row = u >> 3, seg = u & 7;
        uint4 v = *(const uint4*)(w1b + row * CC + seg * 8);
        *(uint4*)(&w1L[row][seg * 8]) = v;
    }
    if (t < 128) {
        int row = t >> 3, seg = t & 7;
        uint4 v = *(const uint4*)(w2bT + row * CC + seg * 8);
        *(uint4*)(&w2L[row][seg * 8]) = v;
    }
    __syncthreads();

    // ---- prologue: GEMM for row i0 into kS[0] (reads slot 1, init-staged) ----
    gemm_chain(1, 0, (b * HH + i0) * WW + j0);

    // ---- epochs: GEMM(r+1) || invol(r), land row r+2, barrier ----
#pragma unroll
    for (int r = 0; r < ROWS; ++r) {
        const int i = i0 + r;
        const int p0 = (b * HH + i) * WW + j0;
        const int cur = r & 1, alt = cur ^ 1;
        const int sTop = r & 3, sMid = (r + 1) & 3, sBot = (r + 2) & 3, sNew = (r + 3) & 3;

        // T14: issue stage loads for row i0+r+2 (lands as slot sNew at epoch end)
        float4 sv[5];
        if (r < ROWS - 1) stage_row_to_regs(i0 + r + 2, sv);

        // GEMM chain for NEXT row (i0+r+1) into kS[alt]; reads sBot (= sMid(r+1))
        if (r < ROWS - 1)
            gemm_chain(sBot, alt, (b * HH + (i + 1)) * WW + j0);

        // involution for CURRENT row from kS[cur] (produced last epoch / prologue)
        {
            float* obase = out + (size_t)(p0 + w * 16) * CC;
#pragma unroll
            for (int rr = 0; rr < 4; ++rr) {
                const int flat = rr * 64 + l;
                const int pxo = flat >> 4;
                const int g = flat & 15;
                const int pix = w * 16 + pxo;
                // vectorized kern load: 3 x b128
                f32x4 k0 = *(const f32x4*)(&kS[cur][pix][0]);
                f32x4 k1 = *(const f32x4*)(&kS[cur][pix][4]);
                f32x4 k2 = *(const f32x4*)(&kS[cur][pix][8]);
                float kern[KK] = {k0[0], k0[1], k0[2], k0[3], k1[0], k1[1], k1[2], k1[3], k2[0]};
                float a0 = 0.f, a1 = 0.f, a2 = 0.f, a3 = 0.f;
#pragma unroll
                for (int ti = 0; ti < 3; ++ti) {
                    const int ii = i + ti - 1;
                    if (ii < 0 || ii >= HH) continue;      // block-uniform skip
                    const int sl = (ti == 0) ? sTop : (ti == 1) ? sMid : sBot;
#pragma unroll
                    for (int tj = 0; tj < 3; ++tj) {
                        int jj = j0 + pix + tj - 1;
                        bool valid = (jj >= 0) && (jj < WW);
                        float kv = valid ? kern[ti * 3 + tj] : 0.f;
                        uint2 u = *(const uint2*)(&xrow[sl][pix + tj][g * 4]);
                        a0 = fmaf(kv, bflo(u.x), a0);
                        a1 = fmaf(kv, bfhi(u.x), a1);
                        a2 = fmaf(kv, bflo(u.y), a2);
                        a3 = fmaf(kv, bfhi(u.y), a3);
                    }
                }
                *(f32x4*)(obase + (size_t)flat * 4) = (f32x4){a0, a1, a2, a3};
            }
        }

        // land next row into dead ring slot; barrier bounds cross-wave halo reads
        if (r < ROWS - 1) {
            write_row_to_lds(sNew, sv);
            __syncthreads();
        }
    }
}

extern "C" void kernel_launch(void* const* d_in, const int* in_sizes, int n_in,
                              void* d_out, int out_size, void* d_ws, size_t ws_size,
                              hipStream_t stream) {
    const float* x       = (const float*)d_in[0];
    const float* w1      = (const float*)d_in[1];
    const float* b1      = (const float*)d_in[2];
    const float* gamma   = (const float*)d_in[3];
    const float* beta    = (const float*)d_in[4];
    const float* bn_mean = (const float*)d_in[5];
    const float* bn_var  = (const float*)d_in[6];
    const float* w2      = (const float*)d_in[7];
    const float* b2      = (const float*)d_in[8];

    ushort_t* w1b  = (ushort_t*)d_ws;                // 4096 ush = 8192 B
    ushort_t* w2bT = w1b + CC * CC;                  // 1024 ush = 2048 B
    float* scalef  = (float*)(w2bT + 16 * CC);       // 64
    float* biasf   = scalef + CC;                    // 64
    float* b2f     = biasf + CC;                     // 9

    float* out  = (float*)d_out;
    float* kout = out + (size_t)NPIX * CC;

    hipLaunchKernelGGL(setup_kernel, dim3(20), dim3(256), 0, stream,
                       w1, b1, gamma, beta, bn_mean, bn_var, w2, b2,
                       w1b, w2bT, scalef, biasf, b2f);

    hipLaunchKernelGGL(invol_fused, dim3(NBLK), dim3(256), 0, stream,
                       x, w1b, w2bT, scalef, biasf, b2f, out, kout);
}